// Round 5
// baseline (336.848 us; speedup 1.0000x reference)
//
#include <hip/hip_runtime.h>

// DigitCaps dynamic routing, B=512, N=4608, IN=16, OUT=32, CAPS=32.
// Identity: b-logits start at zero => softmax stays exactly uniform (1/32)
// across all 3 routing iterations (v is c-independent, so the agreement
// update is constant across c). Hence:
//   v[b,c,k] = squash_k((1/32) * sum_{n,j} x[b,n,j]*W[n,j,k])  for all c
// => one GEMM S[512,32] = X[512,73728] @ Wflat[73728,32], squash, broadcast.
//
// R5: FUSED single kernel (wt_prep -> mfma gemm -> finalize) with two
// device-scope atomic grid barriers. R3 vs R4 (2x occupancy, restructured
// loop) were identical => gemm is at its x-BW floor; remaining suspect is
// per-graph-node boundary cost (launch + L2 flush) of the 3-kernel chain.
// 512 blocks x 256 thr, no LDS, low VGPR => 2 blocks/CU, all co-resident,
// spin barrier safe. Counters zeroed by an 8-byte hipMemsetAsync node.

#define NB 512
#define KTOT 73728          // N*IN
#define OUTC 32
#define NCAPS 32

#define NBLK 512
#define KSPLIT 64
#define KCHUNK (KTOT / KSPLIT)        // 1152
#define NSTEP (KCHUNK / 32)           // 36 k-steps of 32
#define NSTEPS_TOT (KTOT / 32)        // 2304
#define FRAG_U4 (NSTEPS_TOT * 128)    // 294912 uint4 fragments in wt
#define WT_BYTES ((size_t)NSTEPS_TOT * 2048)             // 4,718,592
#define SPA_BYTES ((size_t)KSPLIT * NB * OUTC * 4)       // 4,194,304
#define S_BYTES ((size_t)NB * OUTC * 4)                  // 65,536
#define CNT_OFF (WT_BYTES + SPA_BYTES)
#define WS_NEED_A (CNT_OFF + 64)

typedef short bf16x8 __attribute__((ext_vector_type(8)));
typedef float f32x4 __attribute__((ext_vector_type(4)));

__device__ __forceinline__ unsigned int f2bf(float f) {
    union { float f; unsigned int u; } v; v.f = f;
    unsigned int u = v.u;
    return (u + 0x7fffu + ((u >> 16) & 1u)) >> 16;   // RNE to bf16 bits
}

// device-scope grid barrier: release on arrival, acquire on pass.
// Safe only because all NBLK blocks are co-resident (2 blocks/CU).
__device__ __forceinline__ void grid_barrier(unsigned* cnt, unsigned target) {
    __syncthreads();
    if (threadIdx.x == 0) {
        __hip_atomic_fetch_add(cnt, 1u, __ATOMIC_ACQ_REL,
                               __HIP_MEMORY_SCOPE_AGENT);
        while (__hip_atomic_load(cnt, __ATOMIC_ACQUIRE,
                                 __HIP_MEMORY_SCOPE_AGENT) < target)
            __builtin_amdgcn_s_sleep(8);
    }
    __syncthreads();
}

// ---- fused: wt_prep | barrier | streaming MFMA gemm | barrier | finalize ----
// wt fragment layout: [step][chalf][lane][j] bf16; B[k=step*32+(lane>>4)*8+j]
// [c=chalf*16+(lane&15)]. A-frag: A[m=lane&15][k=(lane>>4)*8+j]. C/D:
// col=lane&15, row=(lane>>4)*4+reg. (All verified R3.)
__global__ __launch_bounds__(256, 2) void digitcaps_fused(
        const float* __restrict__ x, const float* __restrict__ w,
        float* __restrict__ out, char* __restrict__ ws) {
    unsigned short* wt = (unsigned short*)ws;
    float* S = (float*)(ws + WT_BYTES);
    unsigned* cnt = (unsigned*)(ws + CNT_OFF);
    const int t = threadIdx.x;

    // ================= phase 0: W -> bf16 B-fragment layout =================
    for (int tt = blockIdx.x * 256 + t; tt < FRAG_U4; tt += NBLK * 256) {
        int lane = tt & 63;
        int h = (tt >> 6) & 1;
        int step = tt >> 7;
        int k0 = step * 32 + ((lane >> 4) & 3) * 8;
        int c = h * 16 + (lane & 15);
        const float* wp = w + (size_t)k0 * OUTC + c;
        unsigned int u[4];
#pragma unroll
        for (int j = 0; j < 4; ++j) {
            unsigned int lo = f2bf(wp[(2 * j) * OUTC]);
            unsigned int hi = f2bf(wp[(2 * j + 1) * OUTC]);
            u[j] = lo | (hi << 16);
        }
        *(uint4*)(wt + (size_t)tt * 8) = make_uint4(u[0], u[1], u[2], u[3]);
    }

    grid_barrier(cnt, NBLK);

    // ================= phase 1: streaming MFMA GEMM (no LDS) ================
    {
        const int lane = t & 63;
        const int wave = t >> 6;
        const int bx = blockIdx.x & (KSPLIT - 1);   // k-split index
        const int by = blockIdx.x >> 6;             // row-group (8)
        const int row0 = by * 64 + wave * 16;
        const int m = lane & 15;
        const int q = lane >> 4;
        const size_t kbase = (size_t)bx * KCHUNK;

        const float* xp = x + (size_t)(row0 + m) * KTOT + kbase + q * 8;
        const unsigned short* wp = wt + (kbase >> 5) * 1024 + lane * 8;

        f32x4 acc0 = {0.f, 0.f, 0.f, 0.f};
        f32x4 acc1 = {0.f, 0.f, 0.f, 0.f};

        float4 xa = *(const float4*)xp;
        float4 xb = *(const float4*)(xp + 4);
        bf16x8 b0 = *(const bf16x8*)(wp);
        bf16x8 b1 = *(const bf16x8*)(wp + 512);

#pragma unroll 6
        for (int s = 0; s < NSTEP; ++s) {
            float4 nxa, nxb;
            bf16x8 nb0, nb1;
            if (s + 1 < NSTEP) {
                const float* xn = xp + 32;
                nxa = *(const float4*)xn;
                nxb = *(const float4*)(xn + 4);
                const unsigned short* wn = wp + 1024;
                nb0 = *(const bf16x8*)(wn);
                nb1 = *(const bf16x8*)(wn + 512);
            }
            xp += 32;
            wp += 1024;

            bf16x8 a;
            a[0] = (short)f2bf(xa.x); a[1] = (short)f2bf(xa.y);
            a[2] = (short)f2bf(xa.z); a[3] = (short)f2bf(xa.w);
            a[4] = (short)f2bf(xb.x); a[5] = (short)f2bf(xb.y);
            a[6] = (short)f2bf(xb.z); a[7] = (short)f2bf(xb.w);
            acc0 = __builtin_amdgcn_mfma_f32_16x16x32_bf16(a, b0, acc0, 0, 0, 0);
            acc1 = __builtin_amdgcn_mfma_f32_16x16x32_bf16(a, b1, acc1, 0, 0, 0);

            xa = nxa; xb = nxb; b0 = nb0; b1 = nb1;
        }

        // epilogue: C/D col = m, row_local = q*4 + reg -> split-K partials
#pragma unroll
        for (int r = 0; r < 4; ++r) {
            const int row = row0 + q * 4 + r;
            float* dst = S + ((size_t)bx * NB + row) * OUTC;
            dst[m] = acc0[r];
            dst[16 + m] = acc1[r];
        }
    }

    grid_barrier(cnt + 1, NBLK);

    // ================= phase 2: reduce partials, squash, broadcast ==========
    if (t < 64) {
        const int b = blockIdx.x;        // NBLK == NB: one batch row per block
        const int k = t & 31;
        const int h = t >> 5;
        float a = 0.0f;
#pragma unroll 8
        for (int i = 0; i < KSPLIT / 2; ++i)
            a += S[((size_t)(h * (KSPLIT / 2) + i) * NB + b) * OUTC + k];
        a += __shfl_xor(a, 32, 64);      // combine the two halves
        float s = a * (1.0f / 32.0f);
        float sq = s * s;
        sq += __shfl_xor(sq, 16, 64);
        sq += __shfl_xor(sq, 8, 64);
        sq += __shfl_xor(sq, 4, 64);
        sq += __shfl_xor(sq, 2, 64);
        sq += __shfl_xor(sq, 1, 64);
        float scale = sq / ((1.0f + sq) * sqrtf(sq));   // squash
        float v = s * scale;
        float* orow = out + (size_t)b * (NCAPS * OUTC);
#pragma unroll
        for (int j = 0; j < 16; ++j)
            orow[(h + j * 2) * OUTC + k] = v;           // broadcast capsules
    }
}

// =================== fallback path (R4 3-kernel, atomic tier) ===============
__global__ __launch_bounds__(256) void wt_prep(const float* __restrict__ w,
                                               unsigned short* __restrict__ wt) {
    int tt = blockIdx.x * 256 + threadIdx.x;
    int lane = tt & 63;
    int h = (tt >> 6) & 1;
    int step = tt >> 7;
    int k0 = step * 32 + ((lane >> 4) & 3) * 8;
    int c = h * 16 + (lane & 15);
    const float* wp = w + (size_t)k0 * OUTC + c;
    unsigned int u[4];
#pragma unroll
    for (int j = 0; j < 4; ++j) {
        unsigned int lo = f2bf(wp[(2 * j) * OUTC]);
        unsigned int hi = f2bf(wp[(2 * j + 1) * OUTC]);
        u[j] = lo | (hi << 16);
    }
    *(uint4*)(wt + (size_t)tt * 8) = make_uint4(u[0], u[1], u[2], u[3]);
}

__global__ __launch_bounds__(256) void zero_s(float* __restrict__ S) {
    int i = blockIdx.x * 256 + threadIdx.x;
    if (i < NB * OUTC) S[i] = 0.0f;
}

__global__ __launch_bounds__(256) void gemm_mfma_at(
        const float* __restrict__ x, const unsigned short* __restrict__ wt,
        float* __restrict__ S) {
    const int t = threadIdx.x;
    const int lane = t & 63;
    const int wave = t >> 6;
    const int bx = blockIdx.x;
    const int by = blockIdx.y;
    const int row0 = by * 64 + wave * 16;
    const int m = lane & 15;
    const int q = lane >> 4;
    const size_t kbase = (size_t)bx * KCHUNK;
    const float* xp = x + (size_t)(row0 + m) * KTOT + kbase + q * 8;
    const unsigned short* wp = wt + (kbase >> 5) * 1024 + lane * 8;
    f32x4 acc0 = {0.f, 0.f, 0.f, 0.f};
    f32x4 acc1 = {0.f, 0.f, 0.f, 0.f};
#pragma unroll 6
    for (int s = 0; s < NSTEP; ++s) {
        float4 xa = *(const float4*)xp;
        float4 xb = *(const float4*)(xp + 4);
        xp += 32;
        bf16x8 b0 = *(const bf16x8*)(wp);
        bf16x8 b1 = *(const bf16x8*)(wp + 512);
        wp += 1024;
        bf16x8 a;
        a[0] = (short)f2bf(xa.x); a[1] = (short)f2bf(xa.y);
        a[2] = (short)f2bf(xa.z); a[3] = (short)f2bf(xa.w);
        a[4] = (short)f2bf(xb.x); a[5] = (short)f2bf(xb.y);
        a[6] = (short)f2bf(xb.z); a[7] = (short)f2bf(xb.w);
        acc0 = __builtin_amdgcn_mfma_f32_16x16x32_bf16(a, b0, acc0, 0, 0, 0);
        acc1 = __builtin_amdgcn_mfma_f32_16x16x32_bf16(a, b1, acc1, 0, 0, 0);
    }
#pragma unroll
    for (int r = 0; r < 4; ++r) {
        const int row = row0 + q * 4 + r;
        atomicAdd(&S[(size_t)row * OUTC + m], acc0[r]);
        atomicAdd(&S[(size_t)row * OUTC + 16 + m], acc1[r]);
    }
}

__global__ __launch_bounds__(64) void finalize_at(const float* __restrict__ S,
                                                  float* __restrict__ out) {
    const int b = blockIdx.x;
    const int t = threadIdx.x;
    const int k = t & 31;
    const int h = t >> 5;
    float s = S[(size_t)b * OUTC + k] * (1.0f / 32.0f);
    float sq = s * s;
    sq += __shfl_xor(sq, 16, 64);
    sq += __shfl_xor(sq, 8, 64);
    sq += __shfl_xor(sq, 4, 64);
    sq += __shfl_xor(sq, 2, 64);
    sq += __shfl_xor(sq, 1, 64);
    float scale = sq / ((1.0f + sq) * sqrtf(sq));
    float v = s * scale;
    float* orow = out + (size_t)b * (NCAPS * OUTC);
#pragma unroll
    for (int j = 0; j < 16; ++j)
        orow[(h + j * 2) * OUTC + k] = v;
}
// ============================================================================

extern "C" void kernel_launch(void* const* d_in, const int* in_sizes, int n_in,
                              void* d_out, int out_size, void* d_ws, size_t ws_size,
                              hipStream_t stream) {
    const float* x = (const float*)d_in[0];          // [512, 4608, 16] f32
    const float* w = (const float*)d_in[1];          // [4608, 16, 32] f32
    float* out = (float*)d_out;                      // [512, 32, 32] f32

    if (ws_size >= WS_NEED_A) {
        // zero the two barrier counters, then one fused kernel
        hipMemsetAsync((char*)d_ws + CNT_OFF, 0, 64, stream);
        hipLaunchKernelGGL(digitcaps_fused, dim3(NBLK), dim3(256), 0, stream,
                           x, w, out, (char*)d_ws);
    } else if (ws_size >= WT_BYTES + S_BYTES) {
        unsigned short* wt = (unsigned short*)d_ws;
        float* S = (float*)((char*)d_ws + WT_BYTES);
        hipLaunchKernelGGL(wt_prep, dim3(NSTEPS_TOT * 128 / 256), dim3(256), 0,
                           stream, w, wt);
        hipLaunchKernelGGL(zero_s, dim3((NB * OUTC + 255) / 256), dim3(256), 0,
                           stream, S);
        hipLaunchKernelGGL(gemm_mfma_at, dim3(KSPLIT, 8), dim3(256), 0,
                           stream, x, wt, S);
        hipLaunchKernelGGL(finalize_at, dim3(NB), dim3(64), 0, stream, S, out);
    }
    // (ws_size is 600+ MB in this harness; tiers above always suffice)
}

// Round 6
// 229.383 us; speedup vs baseline: 1.4685x; 1.4685x over previous
//
#include <hip/hip_runtime.h>

// DigitCaps dynamic routing, B=512, N=4608, IN=16, OUT=32, CAPS=32.
// Identity: b-logits start at zero => softmax stays exactly uniform (1/32)
// across all 3 routing iterations (v is c-independent, so the agreement
// update is constant across c). Hence:
//   v[b,c,k] = squash_k((1/32) * sum_{n,j} x[b,n,j]*W[n,j,k])  for all c
// => one GEMM S[512,32] = X[512,73728] @ Wflat[73728,32], squash, broadcast.
//
// R6: R5's software grid barrier collapsed (512 blocks spinning on one
// device-scope cacheline across 8 XCDs: 191 us, all pipes idle). Graph-node
// chaining is cheap by comparison -> revert to kernel chain, but fold
// wt_prep INTO the gemm: each block converts its own W k-chunk to bf16
// B-fragments in LDS (73,728 B => exactly 2 blocks/CU, 8 waves/CU, same as
// R4). Removes one node + dependency + the global wt round-trip. K-loop:
// 2 conflict-free ds_read_b128 + 2 x loads + 2 MFMAs per step.

#define NB 512
#define KTOT 73728          // N*IN
#define OUTC 32
#define NCAPS 32

#define KSPLIT 64
#define KCHUNK (KTOT / KSPLIT)        // 1152
#define NSTEP (KCHUNK / 32)           // 36 k-steps of 32
#define SPA_BYTES ((size_t)KSPLIT * NB * OUTC * 4)       // 4,194,304
#define S_BYTES ((size_t)NB * OUTC * 4)                  // 65,536

typedef short bf16x8 __attribute__((ext_vector_type(8)));
typedef float f32x4 __attribute__((ext_vector_type(4)));

__device__ __forceinline__ unsigned int f2bf(float f) {
    union { float f; unsigned int u; } v; v.f = f;
    unsigned int u = v.u;
    return (u + 0x7fffu + ((u >> 16) & 1u)) >> 16;   // RNE to bf16 bits
}

// ---- fused-prep streaming MFMA GEMM ----
// LDS fragment layout (verified R3): entry e = step*128 + h*64 + lane holds
// B[k = step*32 + ((lane>>4)&3)*8 + j][c = h*16 + (lane&15)], j=0..7.
// A-frag: A[m=lane&15][k=(lane>>4)*8+j]. C/D: col=lane&15, row=(lane>>4)*4+reg.
template <bool PART>
__global__ __launch_bounds__(256, 2) void gemm2(
        const float* __restrict__ x, const float* __restrict__ w,
        float* __restrict__ S) {
    __shared__ unsigned short wf[NSTEP * 2 * 64 * 8];   // 73,728 B
    const int t = threadIdx.x;
    const int lane = t & 63;
    const int wave = t >> 6;
    const int bx = blockIdx.x;               // k-split index (64)
    const int by = blockIdx.y;               // row-group (8)
    const size_t kbase = (size_t)bx * KCHUNK;

    // ---- phase 0: convert this block's W chunk into LDS fragments ----
#pragma unroll
    for (int i = 0; i < 18; ++i) {
        int e = i * 256 + t;                 // 0 .. 4607
        int le = e & 63;
        int h = (e >> 6) & 1;
        int st = e >> 7;                     // 0 .. 35
        int k0 = st * 32 + ((le >> 4) & 3) * 8;
        int c = h * 16 + (le & 15);
        const float* wp = w + (kbase + k0) * (size_t)OUTC + c;
        unsigned int u[4];
#pragma unroll
        for (int j = 0; j < 4; ++j) {
            unsigned int lo = f2bf(wp[(2 * j) * OUTC]);
            unsigned int hi = f2bf(wp[(2 * j + 1) * OUTC]);
            u[j] = lo | (hi << 16);
        }
        *(uint4*)&wf[(size_t)e * 8] = make_uint4(u[0], u[1], u[2], u[3]);
    }
    __syncthreads();

    // ---- phase 1: stream x, MFMA (2-deep x prefetch) ----
    const int row0 = by * 64 + wave * 16;
    const int m = lane & 15;
    const int q = lane >> 4;
    const float* xp = x + (size_t)(row0 + m) * KTOT + kbase + q * 8;

    f32x4 acc0 = {0.f, 0.f, 0.f, 0.f};
    f32x4 acc1 = {0.f, 0.f, 0.f, 0.f};

    float4 xa = *(const float4*)xp;
    float4 xb = *(const float4*)(xp + 4);

#pragma unroll 6
    for (int s = 0; s < NSTEP; ++s) {
        float4 nxa, nxb;
        if (s + 1 < NSTEP) {
            const float* xn = xp + 32;
            nxa = *(const float4*)xn;
            nxb = *(const float4*)(xn + 4);
        }
        xp += 32;

        bf16x8 b0 = *(const bf16x8*)&wf[(s * 2 + 0) * 512 + lane * 8];
        bf16x8 b1 = *(const bf16x8*)&wf[(s * 2 + 1) * 512 + lane * 8];

        bf16x8 a;
        a[0] = (short)f2bf(xa.x); a[1] = (short)f2bf(xa.y);
        a[2] = (short)f2bf(xa.z); a[3] = (short)f2bf(xa.w);
        a[4] = (short)f2bf(xb.x); a[5] = (short)f2bf(xb.y);
        a[6] = (short)f2bf(xb.z); a[7] = (short)f2bf(xb.w);
        acc0 = __builtin_amdgcn_mfma_f32_16x16x32_bf16(a, b0, acc0, 0, 0, 0);
        acc1 = __builtin_amdgcn_mfma_f32_16x16x32_bf16(a, b1, acc1, 0, 0, 0);

        xa = nxa; xb = nxb;
    }

    // ---- epilogue: C/D col = m, row_local = q*4 + reg ----
#pragma unroll
    for (int r = 0; r < 4; ++r) {
        const int row = row0 + q * 4 + r;
        if (PART) {
            float* dst = S + ((size_t)bx * NB + row) * OUTC;
            dst[m] = acc0[r];
            dst[16 + m] = acc1[r];
        } else {
            atomicAdd(&S[(size_t)row * OUTC + m], acc0[r]);
            atomicAdd(&S[(size_t)row * OUTC + 16 + m], acc1[r]);
        }
    }
}

__global__ __launch_bounds__(256) void zero_s(float* __restrict__ S) {
    int i = blockIdx.x * 256 + threadIdx.x;
    if (i < NB * OUTC) S[i] = 0.0f;
}

// finalize: sum split-K partials (if PART), scale 1/32, squash, broadcast.
template <bool PART>
__global__ __launch_bounds__(64) void finalize_k(const float* __restrict__ S,
                                                 float* __restrict__ out) {
    const int b = blockIdx.x;
    const int t = threadIdx.x;
    const int k = t & 31;
    const int h = t >> 5;
    float s;
    if (PART) {
        float a = 0.0f;
#pragma unroll 8
        for (int i = 0; i < KSPLIT / 2; ++i)
            a += S[((size_t)(h * (KSPLIT / 2) + i) * NB + b) * OUTC + k];
        a += __shfl_xor(a, 32, 64);     // combine the two halves
        s = a * (1.0f / 32.0f);
    } else {
        s = S[(size_t)b * OUTC + k] * (1.0f / 32.0f);
    }
    float sq = s * s;
    sq += __shfl_xor(sq, 16, 64);
    sq += __shfl_xor(sq, 8, 64);
    sq += __shfl_xor(sq, 4, 64);
    sq += __shfl_xor(sq, 2, 64);
    sq += __shfl_xor(sq, 1, 64);
    float scale = sq / ((1.0f + sq) * sqrtf(sq));   // squash
    float v = s * scale;
    float* orow = out + (size_t)b * (NCAPS * OUTC);
#pragma unroll
    for (int j = 0; j < 16; ++j)
        orow[(h + j * 2) * OUTC + k] = v;           // broadcast across capsules
}

extern "C" void kernel_launch(void* const* d_in, const int* in_sizes, int n_in,
                              void* d_out, int out_size, void* d_ws, size_t ws_size,
                              hipStream_t stream) {
    const float* x = (const float*)d_in[0];          // [512, 4608, 16] f32
    const float* w = (const float*)d_in[1];          // [4608, 16, 32] f32
    float* out = (float*)d_out;                      // [512, 32, 32] f32
    float* S = (float*)d_ws;

    if (ws_size >= SPA_BYTES) {
        // Tier A: split-K partials (no atomics, no zeroing) — 2 nodes total
        hipLaunchKernelGGL((gemm2<true>), dim3(KSPLIT, 8), dim3(256), 0,
                           stream, x, w, S);
        hipLaunchKernelGGL((finalize_k<true>), dim3(NB), dim3(64), 0, stream,
                           S, out);
    } else {
        // Tier B: atomic accumulation into 64 KB S
        hipLaunchKernelGGL(zero_s, dim3((NB * OUTC + 255) / 256), dim3(256), 0,
                           stream, S);
        hipLaunchKernelGGL((gemm2<false>), dim3(KSPLIT, 8), dim3(256), 0,
                           stream, x, w, S);
        hipLaunchKernelGGL((finalize_k<false>), dim3(NB), dim3(64), 0, stream,
                           S, out);
    }
}

// Round 7
// 228.231 us; speedup vs baseline: 1.4759x; 1.0050x over previous
//
#include <hip/hip_runtime.h>

// DigitCaps dynamic routing, B=512, N=4608, IN=16, OUT=32, CAPS=32.
// Identity: b-logits start at zero => softmax stays exactly uniform (1/32)
// across all 3 routing iterations (v is c-independent, so the agreement
// update is constant across c). Hence:
//   v[b,c,k] = squash_k((1/32) * sum_{n,j} x[b,n,j]*W[n,j,k])  for all c
// => one GEMM S[512,32] = X[512,73728] @ Wflat[73728,32], squash, broadcast.
//
// R7: latency-product push (discriminator). R3/R4/R6 all ~227 us despite
// structural rewrites; deduced gemm ~60-75 us at only ~2.1 TB/s x-stream.
// Theory: x-load latency under-covered (8 waves/CU x 1-step prefetch).
// This round: KSPLIT 128 (LDS 36,864 B -> 4 blocks/CU = 16 waves/CU) +
// 4-deep x prefetch (full-unrolled 18-step K-loop). If total doesn't move,
// the residual is harness/graph floor and we're at roofline.

#define NB 512
#define KTOT 73728          // N*IN
#define OUTC 32
#define NCAPS 32

#define KSPLIT 128
#define KCHUNK (KTOT / KSPLIT)        // 576
#define NSTEP (KCHUNK / 32)           // 18 k-steps of 32
#define NENT (NSTEP * 128)            // 2304 LDS fragment uint4s
#define SPA_BYTES ((size_t)KSPLIT * NB * OUTC * 4)       // 8,388,608
#define S_BYTES ((size_t)NB * OUTC * 4)                  // 65,536

typedef short bf16x8 __attribute__((ext_vector_type(8)));
typedef float f32x4 __attribute__((ext_vector_type(4)));

__device__ __forceinline__ unsigned int f2bf(float f) {
    union { float f; unsigned int u; } v; v.f = f;
    unsigned int u = v.u;
    return (u + 0x7fffu + ((u >> 16) & 1u)) >> 16;   // RNE to bf16 bits
}

// ---- fused-prep streaming MFMA GEMM, 16 waves/CU, 4-deep x prefetch ----
// LDS fragment layout (verified R3): entry e = step*128 + h*64 + lane holds
// B[k = step*32 + ((lane>>4)&3)*8 + j][c = h*16 + (lane&15)], j=0..7.
// A-frag: A[m=lane&15][k=(lane>>4)*8+j]. C/D: col=lane&15, row=(lane>>4)*4+reg.
template <bool PART>
__global__ __launch_bounds__(256, 4) void gemm3(
        const float* __restrict__ x, const float* __restrict__ w,
        float* __restrict__ S) {
    __shared__ unsigned short wf[NENT * 8];   // 36,864 B -> 4 blocks/CU
    const int t = threadIdx.x;
    const int lane = t & 63;
    const int wave = t >> 6;
    const int bx = blockIdx.x;               // k-split index (128)
    const int by = blockIdx.y;               // row-group (8)
    const size_t kbase = (size_t)bx * KCHUNK;

    // ---- phase 0: convert this block's W chunk into LDS fragments ----
#pragma unroll
    for (int i = 0; i < NENT / 256; ++i) {   // 9 iterations
        int e = i * 256 + t;                 // 0 .. 2303
        int le = e & 63;
        int h = (e >> 6) & 1;
        int st = e >> 7;                     // 0 .. 17
        int k0 = st * 32 + ((le >> 4) & 3) * 8;
        int c = h * 16 + (le & 15);
        const float* wp = w + (kbase + k0) * (size_t)OUTC + c;
        unsigned int u[4];
#pragma unroll
        for (int j = 0; j < 4; ++j) {
            unsigned int lo = f2bf(wp[(2 * j) * OUTC]);
            unsigned int hi = f2bf(wp[(2 * j + 1) * OUTC]);
            u[j] = lo | (hi << 16);
        }
        *(uint4*)&wf[(size_t)e * 8] = make_uint4(u[0], u[1], u[2], u[3]);
    }
    __syncthreads();

    // ---- phase 1: stream x with 4-deep prefetch, MFMA ----
    const int row0 = by * 64 + wave * 16;
    const int m = lane & 15;
    const int q = lane >> 4;
    const float* xp = x + (size_t)(row0 + m) * KTOT + kbase + q * 8;

    f32x4 acc0 = {0.f, 0.f, 0.f, 0.f};
    f32x4 acc1 = {0.f, 0.f, 0.f, 0.f};

    float4 pa[4], pb[4];
#pragma unroll
    for (int i = 0; i < 4; ++i) {
        pa[i] = *(const float4*)(xp + i * 32);
        pb[i] = *(const float4*)(xp + i * 32 + 4);
    }

#pragma unroll
    for (int s = 0; s < NSTEP; ++s) {        // fully unrolled: ring idx static
        float4 xa = pa[s & 3];
        float4 xb = pb[s & 3];
        if (s + 4 < NSTEP) {
            pa[s & 3] = *(const float4*)(xp + (s + 4) * 32);
            pb[s & 3] = *(const float4*)(xp + (s + 4) * 32 + 4);
        }

        bf16x8 b0 = *(const bf16x8*)&wf[(s * 128 + lane) * 8];
        bf16x8 b1 = *(const bf16x8*)&wf[(s * 128 + 64 + lane) * 8];

        bf16x8 a;
        a[0] = (short)f2bf(xa.x); a[1] = (short)f2bf(xa.y);
        a[2] = (short)f2bf(xa.z); a[3] = (short)f2bf(xa.w);
        a[4] = (short)f2bf(xb.x); a[5] = (short)f2bf(xb.y);
        a[6] = (short)f2bf(xb.z); a[7] = (short)f2bf(xb.w);
        acc0 = __builtin_amdgcn_mfma_f32_16x16x32_bf16(a, b0, acc0, 0, 0, 0);
        acc1 = __builtin_amdgcn_mfma_f32_16x16x32_bf16(a, b1, acc1, 0, 0, 0);
    }

    // ---- epilogue: C/D col = m, row_local = q*4 + reg ----
#pragma unroll
    for (int r = 0; r < 4; ++r) {
        const int row = row0 + q * 4 + r;
        if (PART) {
            float* dst = S + ((size_t)bx * NB + row) * OUTC;
            dst[m] = acc0[r];
            dst[16 + m] = acc1[r];
        } else {
            atomicAdd(&S[(size_t)row * OUTC + m], acc0[r]);
            atomicAdd(&S[(size_t)row * OUTC + 16 + m], acc1[r]);
        }
    }
}

__global__ __launch_bounds__(256) void zero_s(float* __restrict__ S) {
    int i = blockIdx.x * 256 + threadIdx.x;
    if (i < NB * OUTC) S[i] = 0.0f;
}

// finalize: sum split-K partials (if PART), scale 1/32, squash, broadcast.
template <bool PART>
__global__ __launch_bounds__(64) void finalize_k(const float* __restrict__ S,
                                                 float* __restrict__ out) {
    const int b = blockIdx.x;
    const int t = threadIdx.x;
    const int k = t & 31;
    const int h = t >> 5;
    float s;
    if (PART) {
        float a = 0.0f;
#pragma unroll 8
        for (int i = 0; i < KSPLIT / 2; ++i)
            a += S[((size_t)(h * (KSPLIT / 2) + i) * NB + b) * OUTC + k];
        a += __shfl_xor(a, 32, 64);     // combine the two halves
        s = a * (1.0f / 32.0f);
    } else {
        s = S[(size_t)b * OUTC + k] * (1.0f / 32.0f);
    }
    float sq = s * s;
    sq += __shfl_xor(sq, 16, 64);
    sq += __shfl_xor(sq, 8, 64);
    sq += __shfl_xor(sq, 4, 64);
    sq += __shfl_xor(sq, 2, 64);
    sq += __shfl_xor(sq, 1, 64);
    float scale = sq / ((1.0f + sq) * sqrtf(sq));   // squash
    float v = s * scale;
    float* orow = out + (size_t)b * (NCAPS * OUTC);
#pragma unroll
    for (int j = 0; j < 16; ++j)
        orow[(h + j * 2) * OUTC + k] = v;           // broadcast across capsules
}

extern "C" void kernel_launch(void* const* d_in, const int* in_sizes, int n_in,
                              void* d_out, int out_size, void* d_ws, size_t ws_size,
                              hipStream_t stream) {
    const float* x = (const float*)d_in[0];          // [512, 4608, 16] f32
    const float* w = (const float*)d_in[1];          // [4608, 16, 32] f32
    float* out = (float*)d_out;                      // [512, 32, 32] f32
    float* S = (float*)d_ws;

    if (ws_size >= SPA_BYTES) {
        // Tier A: split-K partials (no atomics, no zeroing) — 2 nodes total
        hipLaunchKernelGGL((gemm3<true>), dim3(KSPLIT, 8), dim3(256), 0,
                           stream, x, w, S);
        hipLaunchKernelGGL((finalize_k<true>), dim3(NB), dim3(64), 0, stream,
                           S, out);
    } else {
        // Tier B: atomic accumulation into 64 KB S
        hipLaunchKernelGGL(zero_s, dim3((NB * OUTC + 255) / 256), dim3(256), 0,
                           stream, S);
        hipLaunchKernelGGL((gemm3<false>), dim3(KSPLIT, 8), dim3(256), 0,
                           stream, x, w, S);
        hipLaunchKernelGGL((finalize_k<false>), dim3(NB), dim3(64), 0, stream,
                           S, out);
    }
}